// Round 9
// baseline (3846.935 us; speedup 1.0000x reference)
//
#include <hip/hip_runtime.h>
#include <stdint.h>

// ---------------------------------------------------------------------------
// Encoder_Processor round 13: SAMPLE-SHARDED pipeline. 7 levels x 4 shards
// (16 samples each) = 28 WGs x 512 thr.
// KEY INSIGHT (missed by R4-R12): the recurrence is per-sample independent --
// no activation ever crosses samples. Sharding by SAMPLES eliminates ALL
// intra-level exchange (R7 spent ~6 fabric RTs/step on h/G1/z all-to-all).
// Each WG computes its 16 samples' full level step (G1 16x512, W1, action,
// gates) with activations in 33KB of local LDS. Cross-WG traffic = 1:1
// producer->consumer FIFO (8KB h + flag per step), using the R4/R7-PROVEN
// sc0sc1 protocol: t+2 producer-ahead poll, fused-asm flag polls (rule #18),
// laundered gate reads, empty issue->vwait windows (R10 spill lesson).
// Weights stream via plain cached loads (L2-hot, read-only, ~770KB/step/WG);
// no resident weights -> ~100 VGPR, no spill risk. Acyclic FIFO -> no
// deadlock. No sc0-only ops (R8/R9 lesson).
// ---------------------------------------------------------------------------

typedef _Float16 f16x8 __attribute__((ext_vector_type(8)));
typedef float    f32x4 __attribute__((ext_vector_type(4)));

static constexpr int SS = 256, BB = 64, DIN = 256, DH = 256, DNN = 512, DA = 64;
static constexpr int FS = 32;   // u32 stride between flags = 128B (own line)

// workspace layout (bytes)
static constexpr size_t OFF_FLAGS = 0;                     // u32[8192] = 32KB
static constexpr size_t OFF_WEMB  = 32768;
static constexpr size_t SZ_WEMB   = (size_t)DIN * DH * 2;
static constexpr size_t OFF_W     = OFF_WEMB + SZ_WEMB;
static constexpr size_t SZ_WU     = (size_t)DH * DNN * 2;
static constexpr size_t OFF_U     = OFF_W + SZ_WU;
static constexpr size_t OFF_W1    = OFF_U + SZ_WU;
static constexpr size_t SZ_W1     = (size_t)DNN * DH * 2;
static constexpr size_t OFF_WA1   = OFF_W1 + SZ_W1;
static constexpr size_t SZ_WA     = (size_t)DH * DA * 2;
static constexpr size_t OFF_UA1   = OFF_WA1 + SZ_WA;
static constexpr size_t OFF_NM    = OFF_UA1 + SZ_WA;       // 8 x 64KB fp32 [t][s]
static constexpr size_t SZ_NM     = (size_t)SS * BB * 4;
static constexpr size_t OFF_HV    = OFF_NM + 8 * SZ_NM;
static constexpr size_t OFF_HB    = (size_t)4 << 20;       // 8 x 8MB f16 frag [t][kq<32][s<64]
static constexpr size_t SZ_HB     = (size_t)SS * BB * DH * 2;
static constexpr size_t WS_NEEDED = OFF_HB + 8 * SZ_HB;

__device__ __forceinline__ float lrelu(float v) { return v >= 0.0f ? v : 0.01f * v; }

// --- coherent (fabric-scope, L1/L2 bypass) asm ops -------------------------
// Loads: value NOT valid until vwait()! Issue and vwait must be ADJACENT
// (no high-pressure code between -- R10 spill hazard). After vwait, only
// MEMORY-op consumers are ordered by the clobber; pure-register consumers
// must be laundered (asm volatile "+v").
__device__ __forceinline__ f32x4 ld128(const f32x4* p) {
  f32x4 r;
  asm volatile("global_load_dwordx4 %0, %1, off sc0 sc1" : "=v"(r) : "v"(p) : "memory");
  return r;
}
__device__ __forceinline__ void st128(f32x4* p, f32x4 v) {
  asm volatile("global_store_dwordx4 %0, %1, off sc0 sc1" :: "v"(p), "v"(v) : "memory");
}
__device__ __forceinline__ float ldf(const float* p) {
  float r;
  asm volatile("global_load_dword %0, %1, off sc0 sc1" : "=v"(r) : "v"(p) : "memory");
  return r;
}
__device__ __forceinline__ void stf(float* p, float v) {
  asm volatile("global_store_dword %0, %1, off sc0 sc1" :: "v"(p), "v"(v) : "memory");
}
__device__ __forceinline__ void stu(unsigned* p, unsigned v) {
  asm volatile("global_store_dword %0, %1, off sc0 sc1" :: "v"(p), "v"(v) : "memory");
}
__device__ __forceinline__ void vwait() {
  asm volatile("s_waitcnt vmcnt(0)" ::: "memory");
  __builtin_amdgcn_sched_barrier(0);
}

// poll one flag; load+wait fused in ONE asm (rule-#18 safe)
__device__ __forceinline__ void pollf(const unsigned* p, unsigned need) {
  #pragma nounroll
  for (int g = 0; g < (1 << 18); ++g) {
    unsigned v;
    asm volatile("global_load_dword %0, %1, off sc0 sc1\n\ts_waitcnt vmcnt(0)"
                 : "=v"(v) : "v"(p) : "memory");
    if (v >= need) return;
    if (g > 64)     __builtin_amdgcn_s_sleep(2);
    else if (g > 8) __builtin_amdgcn_s_sleep(1);
  }
}

// ---------------------------------------------------------------------------
__global__ void zero_flags_k(unsigned* f) {
  #pragma unroll
  for (int i = 0; i < 8; ++i) f[threadIdx.x + 1024 * i] = 0u;
}

// pack fp32 row-major [K][N] into f16 MFMA B-frag order
__global__ void pack_weight_k(const float* __restrict__ src, _Float16* __restrict__ dst,
                              int K, int N) {
  int idx = blockIdx.x * 256 + threadIdx.x;
  if (idx >= K * N) return;
  int k = idx / N, n = idx - k * N;
  int kt = k >> 5, q = (k >> 3) & 3, jj = k & 7;
  int nt = n >> 4, l = n & 15;
  size_t p = (((size_t)(kt * (N >> 4) + nt) * 4 + q) * 16 + l) * 8 + jj;
  dst[p] = (_Float16)src[idx];
}

// ---------------------------------------------------------------------------
// embedding: xe = x@W_emb + b_emb -> level-0 h buffer in FRAG layout
// ---------------------------------------------------------------------------
__global__ __launch_bounds__(512, 2) void emb_k(const float* __restrict__ xin,
                                                const float* __restrict__ b_emb,
                                                char* __restrict__ ws) {
  const int tid = threadIdx.x, wave = tid >> 6, lane = tid & 63;
  const int l15 = lane & 15, quad = lane >> 4;
  const _Float16* Wp = (const _Float16*)(ws + OFF_WEMB);
  _Float16* xe = (_Float16*)(ws + OFF_HB);

  f16x8 bE[16];
  #pragma unroll
  for (int kt = 0; kt < 8; ++kt)
    #pragma unroll
    for (int i = 0; i < 2; ++i)
      bE[kt * 2 + i] = *(const f16x8*)(Wp + (((size_t)(kt * 16 + (wave * 2 + i)) * 4 + quad) * 16 + l15) * 8);
  float ber[2] = { b_emb[(wave * 2) * 16 + l15], b_emb[(wave * 2 + 1) * 16 + l15] };

  __shared__ __align__(16) _Float16 xtF[32 * 65 * 8];
  __shared__ __align__(16) _Float16 oF[32 * 65 * 8];

  for (int tt = 0; tt < 4; ++tt) {
    const int t = (int)blockIdx.x + 64 * tt;
    #pragma unroll
    for (int c = 0; c < 4; ++c) {
      int u = tid + 512 * c, s = u >> 5, kg = u & 31;
      const float* src = xin + ((size_t)s * SS + t) * DIN + kg * 8;
      f32x4 v0 = *(const f32x4*)src, v1 = *(const f32x4*)(src + 4);
      f16x8 p;
      p[0]=(_Float16)v0[0]; p[1]=(_Float16)v0[1]; p[2]=(_Float16)v0[2]; p[3]=(_Float16)v0[3];
      p[4]=(_Float16)v1[0]; p[5]=(_Float16)v1[1]; p[6]=(_Float16)v1[2]; p[7]=(_Float16)v1[3];
      *(f16x8*)(xtF + ((size_t)kg * 65 + s) * 8) = p;
    }
    __syncthreads();
    f32x4 acc[2][4] = {};
    #pragma unroll
    for (int kt = 0; kt < 8; ++kt) {
      f16x8 ax[4];
      #pragma unroll
      for (int mt = 0; mt < 4; ++mt)
        ax[mt] = *(const f16x8*)(xtF + (((size_t)(kt * 4 + quad)) * 65 + (mt * 16 + l15)) * 8);
      #pragma unroll
      for (int i = 0; i < 2; ++i)
        #pragma unroll
        for (int mt = 0; mt < 4; ++mt)
          acc[i][mt] = __builtin_amdgcn_mfma_f32_16x16x32_f16(ax[mt], bE[kt * 2 + i], acc[i][mt], 0, 0, 0);
    }
    #pragma unroll
    for (int i = 0; i < 2; ++i) {
      int n = (wave * 2 + i) * 16 + l15;
      int kq = n >> 3, jn = n & 7;
      #pragma unroll
      for (int mt = 0; mt < 4; ++mt)
        #pragma unroll
        for (int r = 0; r < 4; ++r) {
          int s = mt * 16 + quad * 4 + r;
          oF[((size_t)kq * 65 + s) * 8 + jn] = (_Float16)(acc[i][mt][r] + ber[i]);
        }
    }
    __syncthreads();
    #pragma unroll
    for (int c = 0; c < 4; ++c) {
      int u = tid + 512 * c, kq = u >> 6, s = u & 63;
      f32x4 v = *(const f32x4*)(oF + ((size_t)kq * 65 + s) * 8);
      *((f32x4*)(xe + (((size_t)t * 32 + kq) * 64 + s) * 8)) = v;  // plain; kernel-end flush
    }
    __syncthreads();
  }
}

// ---------------------------------------------------------------------------
// pipeline: 28 WGs = 7 levels x 4 sample-shards (16 samples each), 512 thr.
// Wave w owns G1 n-tiles [w*4,w*4+4), W1/h n-tiles [w*2,w*2+2);
// waves 0-3 also action n-tile = wave. Rows = the shard's 16 samples.
// ---------------------------------------------------------------------------
__global__ __launch_bounds__(512, 2) void pipe_k(
    const float* __restrict__ mask, const float* __restrict__ b_in,
    const float* __restrict__ b1v, const float* __restrict__ bA1,
    const float* __restrict__ WA3, const float* __restrict__ bA3,
    char* __restrict__ ws, float* __restrict__ outp) {
  const int bId   = (int)blockIdx.x;
  const int level = 1 + (bId >> 2);      // 1..7
  const int g     = bId & 3;             // samples [g*16, g*16+16)
  const int tid   = threadIdx.x, wave = tid >> 6, lane = tid & 63;
  const int l15   = lane & 15, quad = lane >> 4;
  const int kq16  = tid >> 4, sp16 = tid & 15;   // FIFO chunk map: tid -> (kq, s')

  unsigned* flags = (unsigned*)(ws + OFF_FLAGS);
  unsigned* hfl   = flags + (size_t)(level * 4 + g) * FS;
  unsigned* hflP  = flags + (size_t)((level - 1) * 4 + g) * FS;

  const _Float16* Wp   = (const _Float16*)(ws + OFF_W);
  const _Float16* Up   = (const _Float16*)(ws + OFF_U);
  const _Float16* W1p  = (const _Float16*)(ws + OFF_W1);
  const _Float16* WA1p = (const _Float16*)(ws + OFF_WA1);
  const _Float16* UA1p = (const _Float16*)(ws + OFF_UA1);

  const f32x4* hPrev4 = (const f32x4*)((_Float16*)(ws + OFF_HB) + (size_t)(level - 1) * SS * BB * DH);
  f32x4*       hOwn4  = (f32x4*)((_Float16*)(ws + OFF_HB) + (size_t)level * SS * BB * DH);
  float*       nmW    = (float*)(ws + OFF_NM + (size_t)level * SZ_NM);
  float*       hvW    = (float*)(ws + OFF_HV + (size_t)level * SZ_NM);
  const float* nmR    = (const float*)(ws + OFF_NM + (size_t)(level - 1) * SZ_NM);
  const float* hvR    = (const float*)(ws + OFF_HV + (size_t)(level - 1) * SZ_NM);

  float bir[4];
  #pragma unroll
  for (int nt = 0; nt < 4; ++nt) bir[nt] = b_in[(wave * 4 + nt) * 16 + l15];
  float b1r[2];
  #pragma unroll
  for (int nt = 0; nt < 2; ++nt) b1r[nt] = b1v[(wave * 2 + nt) * 16 + l15];
  const float wa3r = WA3[(wave & 3) * 16 + l15];
  const float ba1r = bA1[(wave & 3) * 16 + l15];
  const float bA3v = bA3[0];

  // --- LDS (~33 KB), all [kq][s'<16][jj<8] frag-local ---
  __shared__ __align__(16) _Float16 xtL[32 * 16 * 8];   // 8 KB  xt[t]
  __shared__ __align__(16) _Float16 hL [32 * 16 * 8];   // 8 KB  h[t-1] -> h[t]
  __shared__ __align__(16) _Float16 g1L[64 * 16 * 8];   // 16 KB G1
  __shared__ float zL[64];                              // [w<4][s'<16]
  __shared__ float gB[16], gX[16], gH[16], gHv[16];

  for (int i = tid; i < 32 * 16 * 8; i += 512) hL[i] = (_Float16)0;
  if (tid < 16) gHv[tid] = 0.0f;
  __syncthreads();

  // prologue: stage xt[0] (empty issue->vwait window)
  if (level >= 2) pollf(hflP, 1);
  __syncthreads();
  {
    f32x4 v = ld128(hPrev4 + kq16 * 64 + g * 16 + sp16);
    vwait();
    ((f32x4*)xtL)[tid] = v;
  }
  __syncthreads();

  for (int t = 0; t < SS; ++t) {
    const bool last = (t == SS - 1);

    // -- B: producer-ahead poll (prev level >= t+2); gates xt[t+1], nm/hv --
    if (level >= 2) pollf(hflP, (unsigned)((t + 2 <= SS) ? (t + 2) : SS));

    // -- D: G1 = lrelu(xt@W + h@U + b); W,U streamed (plain cached, L2-hot) --
    {
      f32x4 acc[4] = {};
      #pragma unroll
      for (int kt = 0; kt < 8; ++kt) {
        f16x8 ax = *(const f16x8*)(xtL + ((size_t)((kt * 4 + quad) * 16 + l15)) * 8);
        f16x8 ah = *(const f16x8*)(hL  + ((size_t)((kt * 4 + quad) * 16 + l15)) * 8);
        #pragma unroll
        for (int i = 0; i < 4; ++i) {
          f16x8 wf = *(const f16x8*)(Wp + (((size_t)(kt * 32 + (wave * 4 + i)) * 4 + quad) * 16 + l15) * 8);
          f16x8 uf = *(const f16x8*)(Up + (((size_t)(kt * 32 + (wave * 4 + i)) * 4 + quad) * 16 + l15) * 8);
          acc[i] = __builtin_amdgcn_mfma_f32_16x16x32_f16(ax, wf, acc[i], 0, 0, 0);
          acc[i] = __builtin_amdgcn_mfma_f32_16x16x32_f16(ah, uf, acc[i], 0, 0, 0);
        }
      }
      #pragma unroll
      for (int i = 0; i < 4; ++i) {
        const int n = (wave * 4 + i) * 16 + l15;
        const int kqn = n >> 3, jn = n & 7;
        #pragma unroll
        for (int r = 0; r < 4; ++r)
          g1L[((size_t)kqn * 16 + (quad * 4 + r)) * 8 + jn] = (_Float16)lrelu(acc[i][r] + bir[i]);
      }
      if (wave < 4) {    // action MLP, n-tile = wave
        f32x4 aa = {};
        #pragma unroll
        for (int kt = 0; kt < 8; ++kt) {
          f16x8 ax = *(const f16x8*)(xtL + ((size_t)((kt * 4 + quad) * 16 + l15)) * 8);
          f16x8 ah = *(const f16x8*)(hL  + ((size_t)((kt * 4 + quad) * 16 + l15)) * 8);
          f16x8 wa = *(const f16x8*)(WA1p + (((size_t)(kt * 4 + wave) * 4 + quad) * 16 + l15) * 8);
          f16x8 ua = *(const f16x8*)(UA1p + (((size_t)(kt * 4 + wave) * 4 + quad) * 16 + l15) * 8);
          aa = __builtin_amdgcn_mfma_f32_16x16x32_f16(ax, wa, aa, 0, 0, 0);
          aa = __builtin_amdgcn_mfma_f32_16x16x32_f16(ah, ua, aa, 0, 0, 0);
        }
        #pragma unroll
        for (int r = 0; r < 4; ++r) {
          float v = lrelu(aa[r] + ba1r) * wa3r;
          v += __shfl_xor(v, 1); v += __shfl_xor(v, 2);
          v += __shfl_xor(v, 4); v += __shfl_xor(v, 8);
          if (l15 == 0) zL[wave * 16 + quad * 4 + r] = v;
        }
      }
    }
    __syncthreads();   // g1L + zL ready; xtL/hL D-reads done

    // -- W1: c1 = G1 @ W1 (streamed; no asm loads in flight) --
    f32x4 c1[2] = {};
    #pragma unroll
    for (int kt = 0; kt < 16; ++kt) {
      f16x8 ag = *(const f16x8*)(g1L + ((size_t)((kt * 4 + quad) * 16 + l15)) * 8);
      #pragma unroll
      for (int nt = 0; nt < 2; ++nt) {
        f16x8 w1f = *(const f16x8*)(W1p + (((size_t)(kt * 16 + (wave * 2 + nt)) * 4 + quad) * 16 + l15) * 8);
        c1[nt] = __builtin_amdgcn_mfma_f32_16x16x32_f16(ag, w1f, c1[nt], 0, 0, 0);
      }
    }

    // -- G: cross-level loads, EMPTY issue->vwait window (spill-safe) --
    f32x4 pf;
    float pmv = 1.0f, phh = 0.0f;
    {
      const bool wantGate = (tid < 16) && (level >= 2);
      if (!last) pf = ld128(hPrev4 + (size_t)(t + 1) * 2048 + kq16 * 64 + g * 16 + sp16);
      if (wantGate) {
        size_t tn = (t + 1 < SS) ? (size_t)(t + 1) : 0;
        pmv = ldf(nmR + tn * BB + g * 16 + tid);
        phh = ldf(hvR + (size_t)t * BB + g * 16 + tid);
      }
      vwait();
      if (wantGate) asm volatile("" : "+v"(pmv), "+v"(phh));  // rule #18 launder
    }

    // -- H: gates (tid<16, one sample each) --
    if (tid < 16) {
      const int s = tid;
      float pm, phv;
      if (level == 1) {
        float mv = mask[(size_t)(g * 16 + s) * SS + t];   // read-only input
        pm = mv; phv = mv;
      } else {
        pm  = (t + 1 < SS) ? pmv : 1.0f;
        phv = phh;
      }
      float z    = bA3v + zL[s] + zL[16 + s] + zL[32 + s] + zL[48 + s];
      float nm0  = fminf(fmaxf(0.2f * z + 0.5f, 0.0f), 1.0f);
      float lv   = last ? 1.0f : 0.0f;
      float nm   = (1.0f - lv) * (pm * phv * nm0);
      float hvp  = gHv[s], omn = 1.0f - nm;
      float both = pm * phv * omn * hvp;
      float xo   = pm * phv * (nm + omn * (1.0f - hvp));
      float ho   = (1.0f - pm * phv) * omn * hvp;
      float hv   = both + xo + ho;
      gB[s] = both; gX[s] = xo; gH[s] = ho; gHv[s] = hv;
      if (level < 7) {
        stf(&nmW[(size_t)t * BB + g * 16 + s], nm);   // sc1; acked before flag
        stf(&hvW[(size_t)t * BB + g * 16 + s], hv);
      }
    }
    __syncthreads();   // gB/gX/gH ready

    // -- I: combine -> hL (owner-exclusive RMW); level-7 output --
    #pragma unroll
    for (int nt = 0; nt < 2; ++nt) {
      const int n = (wave * 2 + nt) * 16 + l15;
      const int kqc = n >> 3, jc = n & 7;
      #pragma unroll
      for (int r = 0; r < 4; ++r) {
        int s = quad * 4 + r;
        size_t idx = ((size_t)kqc * 16 + s) * 8 + jc;
        float h1  = lrelu(c1[nt][r] + b1r[nt]);
        float xtv = (float)xtL[idx];
        float hp  = (float)hL[idx];
        float hn  = gB[s] * h1 + gX[s] * xtv + gH[s] * hp;
        hL[idx] = (_Float16)hn;
        if (level == 7 && last) outp[(size_t)(g * 16 + s) * DH + n] = hn;
      }
    }
    __syncthreads();   // hL complete; xtL combine-reads done

    // -- publish h[t] (sc1) + rotate xt buffer --
    {
      f32x4 v = ((const f32x4*)hL)[tid];
      st128(hOwn4 + (size_t)t * 2048 + kq16 * 64 + g * 16 + sp16, v);
    }
    if (!last) ((f32x4*)xtL)[tid] = pf;
    vwait();           // h + nm/hv stores acked
    __syncthreads();
    if (tid == 0) stu(hfl, (unsigned)(t + 1));
  }
}

// ---------------------------------------------------------------------------
extern "C" void kernel_launch(void* const* d_in, const int* in_sizes, int n_in,
                              void* d_out, int out_size, void* d_ws, size_t ws_size,
                              hipStream_t stream) {
  const float* x     = (const float*)d_in[0];
  const float* mask  = (const float*)d_in[1];
  const float* W_emb = (const float*)d_in[3];
  const float* b_emb = (const float*)d_in[4];
  const float* W     = (const float*)d_in[5];
  const float* U     = (const float*)d_in[6];
  const float* b     = (const float*)d_in[7];
  const float* W1    = (const float*)d_in[8];
  const float* b1    = (const float*)d_in[9];
  const float* WA1   = (const float*)d_in[10];
  const float* UA1   = (const float*)d_in[11];
  const float* bA1   = (const float*)d_in[12];
  const float* WA3   = (const float*)d_in[13];
  const float* bA3   = (const float*)d_in[14];
  char* ws = (char*)d_ws;

  if (ws_size < WS_NEEDED) return;

  zero_flags_k<<<1, 1024, 0, stream>>>((unsigned*)(ws + OFF_FLAGS));
  pack_weight_k<<<(DIN * DH + 255) / 256, 256, 0, stream>>>(W_emb, (_Float16*)(ws + OFF_WEMB), DIN, DH);
  pack_weight_k<<<(DH * DNN + 255) / 256, 256, 0, stream>>>(W, (_Float16*)(ws + OFF_W), DH, DNN);
  pack_weight_k<<<(DH * DNN + 255) / 256, 256, 0, stream>>>(U, (_Float16*)(ws + OFF_U), DH, DNN);
  pack_weight_k<<<(DNN * DH + 255) / 256, 256, 0, stream>>>(W1, (_Float16*)(ws + OFF_W1), DNN, DH);
  pack_weight_k<<<(DH * DA + 255) / 256, 256, 0, stream>>>(WA1, (_Float16*)(ws + OFF_WA1), DH, DA);
  pack_weight_k<<<(DH * DA + 255) / 256, 256, 0, stream>>>(UA1, (_Float16*)(ws + OFF_UA1), DH, DA);

  emb_k<<<64, 512, 0, stream>>>(x, b_emb, ws);
  pipe_k<<<28, 512, 0, stream>>>(mask, b, b1, bA1, WA3, bA3, ws, (float*)d_out);
}